// Round 15
// baseline (5088.096 us; speedup 1.0000x reference)
//
#include <hip/hip_runtime.h>
#include <stdint.h>

// ---------------------------------------------------------------------------
// GRU encoder (B=128,T=512,D=512,H=512,L=256), MI355X gfx950.
//
// R19: COMBINED poll+data consumer batch, R4 producer kept verbatim.
//   producer (R4-exact): gates -> 4 tagged u32 stores -> s_waitcnt vmcnt(0)
//     (drain) -> flag = t+1. Drain-before-flag => flag=t implies data
//     visible; tags close the tiny flag-flight race window.
//   consumer: loop { ONE asm batch = flag dword (lane&31) + 32 tagged
//     dwordx4 + single vmcnt(0); ok = flag>=t && all 128 tags==t;
//     __all(ok) -> break }. The attempt that observes the flag already
//     carries the data -> R4's separate 1-RT data load disappears.
// R18 failed (absmax 0.226) because it SPLIT load-issue and waitcnt across
// asm blocks: in-flight loads target physical registers the compiler may
// remap between statements. R19 keeps every load+wait in one asm body.
// Components proven: tagged format + store_t4 (+2-row base) R11/R12/R17;
// 32x dwordx4 single-vmcnt batch R12/R17 (R17 passed absmax); Whh-in-LDS
// fragments R17 (VGPR 132, zero bank conflicts); R4 drain-then-flag ring.
// Deadlock-free: producers store+drain+flag unconditionally; consumer
// retries until tags match (eventually true). Worst case slow, never hung.
// hbuf (u32 x2) + flags memset 0 (tag/flag 0 < live values 1..511).
// h_0 = 0 synthesized in registers. ig_gemm / final_linear unchanged.
// ---------------------------------------------------------------------------

typedef short short8 __attribute__((ext_vector_type(8)));
typedef float f32x4 __attribute__((ext_vector_type(4)));
typedef int int4v __attribute__((ext_vector_type(4)));

#define NB 128
#define NT 512
#define ND 512
#define NH 512
#define NG 1536  // 3H

__device__ __forceinline__ unsigned short f2bf(float f) {
  union { float f; unsigned u; } v; v.f = f;
  unsigned r = v.u + 0x7fffu + ((v.u >> 16) & 1u);  // RNE
  return (unsigned short)(r >> 16);
}
__device__ __forceinline__ float bf2f(unsigned short u) {
  union { unsigned u; float f; } v; v.u = ((unsigned)u) << 16; return v.f;
}
__device__ __forceinline__ float sigmoid_f(float x) {
  float e = __builtin_amdgcn_exp2f(-1.4426950408889634f * x);
  return __builtin_amdgcn_rcpf(1.0f + e);
}
__device__ __forceinline__ float tanh_f(float x) {
  float e = __builtin_amdgcn_exp2f(2.8853900817779268f * x);
  return 1.0f - 2.0f * __builtin_amdgcn_rcpf(1.0f + e);
}
__device__ __forceinline__ short8 pack8(float4 a, float4 b) {
  short8 s;
  s[0] = (short)f2bf(a.x); s[1] = (short)f2bf(a.y);
  s[2] = (short)f2bf(a.z); s[3] = (short)f2bf(a.w);
  s[4] = (short)f2bf(b.x); s[5] = (short)f2bf(b.y);
  s[6] = (short)f2bf(b.z); s[7] = (short)f2bf(b.w);
  return s;
}

// ONE batch: flag dword + 32 tagged dwordx4 (lane's 16 chunks at byte
// kk*128 and kk*128+16), single vmcnt(0). Issue and wait in the SAME asm
// body (R18 lesson). p = lane u32 pointer (incl. +q*8); fp = flag pointer.
__device__ __forceinline__ void load_batch(const unsigned* p, const unsigned* fp,
                                           int4v a[32], unsigned* fv) {
  asm volatile(
      "global_load_dword %32, %34, off sc0 sc1\n\t"
      "global_load_dwordx4 %0,  %33, off sc0 sc1\n\t"
      "global_load_dwordx4 %1,  %33, off offset:16 sc0 sc1\n\t"
      "global_load_dwordx4 %2,  %33, off offset:128 sc0 sc1\n\t"
      "global_load_dwordx4 %3,  %33, off offset:144 sc0 sc1\n\t"
      "global_load_dwordx4 %4,  %33, off offset:256 sc0 sc1\n\t"
      "global_load_dwordx4 %5,  %33, off offset:272 sc0 sc1\n\t"
      "global_load_dwordx4 %6,  %33, off offset:384 sc0 sc1\n\t"
      "global_load_dwordx4 %7,  %33, off offset:400 sc0 sc1\n\t"
      "global_load_dwordx4 %8,  %33, off offset:512 sc0 sc1\n\t"
      "global_load_dwordx4 %9,  %33, off offset:528 sc0 sc1\n\t"
      "global_load_dwordx4 %10, %33, off offset:640 sc0 sc1\n\t"
      "global_load_dwordx4 %11, %33, off offset:656 sc0 sc1\n\t"
      "global_load_dwordx4 %12, %33, off offset:768 sc0 sc1\n\t"
      "global_load_dwordx4 %13, %33, off offset:784 sc0 sc1\n\t"
      "global_load_dwordx4 %14, %33, off offset:896 sc0 sc1\n\t"
      "global_load_dwordx4 %15, %33, off offset:912 sc0 sc1\n\t"
      "global_load_dwordx4 %16, %33, off offset:1024 sc0 sc1\n\t"
      "global_load_dwordx4 %17, %33, off offset:1040 sc0 sc1\n\t"
      "global_load_dwordx4 %18, %33, off offset:1152 sc0 sc1\n\t"
      "global_load_dwordx4 %19, %33, off offset:1168 sc0 sc1\n\t"
      "global_load_dwordx4 %20, %33, off offset:1280 sc0 sc1\n\t"
      "global_load_dwordx4 %21, %33, off offset:1296 sc0 sc1\n\t"
      "global_load_dwordx4 %22, %33, off offset:1408 sc0 sc1\n\t"
      "global_load_dwordx4 %23, %33, off offset:1424 sc0 sc1\n\t"
      "global_load_dwordx4 %24, %33, off offset:1536 sc0 sc1\n\t"
      "global_load_dwordx4 %25, %33, off offset:1552 sc0 sc1\n\t"
      "global_load_dwordx4 %26, %33, off offset:1664 sc0 sc1\n\t"
      "global_load_dwordx4 %27, %33, off offset:1680 sc0 sc1\n\t"
      "global_load_dwordx4 %28, %33, off offset:1792 sc0 sc1\n\t"
      "global_load_dwordx4 %29, %33, off offset:1808 sc0 sc1\n\t"
      "global_load_dwordx4 %30, %33, off offset:1920 sc0 sc1\n\t"
      "global_load_dwordx4 %31, %33, off offset:1936 sc0 sc1\n\t"
      "s_waitcnt vmcnt(0)"
      : "=&v"(a[0]), "=&v"(a[1]), "=&v"(a[2]), "=&v"(a[3]),
        "=&v"(a[4]), "=&v"(a[5]), "=&v"(a[6]), "=&v"(a[7]),
        "=&v"(a[8]), "=&v"(a[9]), "=&v"(a[10]), "=&v"(a[11]),
        "=&v"(a[12]), "=&v"(a[13]), "=&v"(a[14]), "=&v"(a[15]),
        "=&v"(a[16]), "=&v"(a[17]), "=&v"(a[18]), "=&v"(a[19]),
        "=&v"(a[20]), "=&v"(a[21]), "=&v"(a[22]), "=&v"(a[23]),
        "=&v"(a[24]), "=&v"(a[25]), "=&v"(a[26]), "=&v"(a[27]),
        "=&v"(a[28]), "=&v"(a[29]), "=&v"(a[30]), "=&v"(a[31]),
        "=&v"(*fv)
      : "v"(p), "v"(fp)
      : "memory");
}

// 4 tagged dword stores (rows erow..erow+3, stride 2048B), base +2 rows so
// 13-bit signed offsets reach all 4. NO internal drain. (R12/R17-proven)
__device__ __forceinline__ void store_t4(unsigned* p2, unsigned v0,
                                         unsigned v1, unsigned v2, unsigned v3) {
  asm volatile(
      "global_store_dword %0, %1, off offset:-4096 sc0 sc1\n\t"
      "global_store_dword %0, %2, off offset:-2048 sc0 sc1\n\t"
      "global_store_dword %0, %3, off sc0 sc1\n\t"
      "global_store_dword %0, %4, off offset:2048 sc0 sc1"
      :
      : "v"(p2), "v"(v0), "v"(v1), "v"(v2), "v"(v3)
      : "memory");
}

__device__ __forceinline__ void flag_store(unsigned* p, unsigned v) {
  asm volatile("global_store_dword %0, %1, off sc0 sc1"
               :: "v"(p), "v"(v) : "memory");
}

// ---------------------------------------------------------------------------
// IG = x @ Wih^T + bias, bf16 out. M=65536, N=1536, K=512. (unchanged)
// ---------------------------------------------------------------------------
__global__ __launch_bounds__(256) void ig_gemm(
    const float* __restrict__ x, const float* __restrict__ Wih,
    const float* __restrict__ bias, unsigned short* __restrict__ IG) {
  __shared__ unsigned short As[128 * 40];
  __shared__ unsigned short Bs[128 * 40];
  const int tid = threadIdx.x;
  const int bm = blockIdx.x, bn = blockIdx.y;
  const int lane = tid & 63, w = tid >> 6;
  const int wm = w >> 1, wn = w & 1;
  const int l15 = lane & 15, q = lane >> 4;

  f32x4 acc[4][4] = {};

  for (int kt = 0; kt < 16; ++kt) {
    __syncthreads();
#pragma unroll
    for (int j = 0; j < 4; ++j) {
      int fi = tid + 256 * j;
      int row = fi >> 3, kq = fi & 7;
      float4 v = *(const float4*)(x + (size_t)(bm * 128 + row) * ND + kt * 32 + kq * 4);
      ushort4 s = {f2bf(v.x), f2bf(v.y), f2bf(v.z), f2bf(v.w)};
      *(ushort4*)&As[row * 40 + kq * 4] = s;
    }
#pragma unroll
    for (int j = 0; j < 4; ++j) {
      int fi = tid + 256 * j;
      int row = fi >> 3, kq = fi & 7;
      float4 v = *(const float4*)(Wih + (size_t)(bn * 128 + row) * ND + kt * 32 + kq * 4);
      ushort4 s = {f2bf(v.x), f2bf(v.y), f2bf(v.z), f2bf(v.w)};
      *(ushort4*)&Bs[row * 40 + kq * 4] = s;
    }
    __syncthreads();

    short8 af[4], bfv[4];
#pragma unroll
    for (int tm = 0; tm < 4; ++tm)
      af[tm] = *(const short8*)&As[(wm * 64 + tm * 16 + l15) * 40 + q * 8];
#pragma unroll
    for (int tn = 0; tn < 4; ++tn)
      bfv[tn] = *(const short8*)&Bs[(wn * 64 + tn * 16 + l15) * 40 + q * 8];
#pragma unroll
    for (int tm = 0; tm < 4; ++tm)
#pragma unroll
      for (int tn = 0; tn < 4; ++tn)
        acc[tm][tn] = __builtin_amdgcn_mfma_f32_16x16x32_bf16(af[tm], bfv[tn], acc[tm][tn], 0, 0, 0);
  }

#pragma unroll
  for (int tm = 0; tm < 4; ++tm) {
#pragma unroll
    for (int tn = 0; tn < 4; ++tn) {
      int col = bn * 128 + wn * 64 + tn * 16 + l15;
      float bb = bias[col];
#pragma unroll
      for (int i = 0; i < 4; ++i) {
        int row = bm * 128 + wm * 64 + tm * 16 + q * 4 + i;
        IG[(size_t)row * NG + col] = f2bf(acc[tm][tn][i] + bb);
      }
    }
  }
}

// ---------------------------------------------------------------------------
// Persistent GRU recurrence. 64 blocks x 256 threads. (R4 topology)
// block = (group g of 32 batch rows, chunk c of 32 h-cols).
// wave (wm,wn): rows [b0+wm*16,+16), cols [c*32+wn*16,+16).
// Whh fragments in LDS (R17). h buffers: u32 tagged (bf16<<16 | step).
// flags[((g*2+wm)*16+c)*2+wn] = step count (stores drained before flag).
// ---------------------------------------------------------------------------
template <bool USE_IG>
__global__ __launch_bounds__(256, 1) void gru_rec(
    const float* __restrict__ x, const float* __restrict__ Wih,
    const float* __restrict__ Whh, const float* __restrict__ bias,
    const float* __restrict__ bn, const unsigned short* __restrict__ IG,
    unsigned* __restrict__ hbuf, unsigned* __restrict__ flags,
    float* __restrict__ hfin) {
  __shared__ short8 Blds[3 * 16 * 4 * 32];  // 96 KB of Whh bf16 fragments

  const int tid = threadIdx.x;
  const int lane = tid & 63;
  const int w = tid >> 6;
  const int wm = w >> 1, wn = w & 1;
  const int l15 = lane & 15, q = lane >> 4;
  const int g = blockIdx.x >> 4;   // 4 groups
  const int c = blockIdx.x & 15;   // 16 col-chunks of 32
  const int b0 = g * 32;
  const int col = c * 32 + wn * 16 + l15;  // this lane's h column
  const int mrow = b0 + wm * 16 + l15;     // A-fragment batch row
  const int erow = b0 + wm * 16 + q * 4;   // C-layout batch row base
  const int ci = wn * 16 + l15;            // Blds col index

  unsigned* const myflag = flags + ((g * 2 + wm) * 16 + c) * 2 + wn;
  const unsigned* const pollbase = flags + (g * 2 + wm) * 32;  // 32 flags

  // Stage Whh fragments -> LDS (R17-proven, zero bank conflicts).
#pragma unroll
  for (int j = 0; j < 24; ++j) {
    int fid = tid + 256 * j;
    int gate = fid >> 11;
    int rem = fid & 2047;
    int kk = rem >> 7;
    int q2 = (rem >> 5) & 3;
    int colIdx = rem & 31;
    const float* src = Whh + (size_t)(gate * NH + c * 32 + colIdx) * NH + kk * 32 + q2 * 8;
    Blds[((gate * 16 + kk) * 4 + q2) * 32 + colIdx] =
        pack8(*(const float4*)src, *(const float4*)(src + 4));
  }
  __syncthreads();

  float bi_r = 0.f, bi_z = 0.f, bi_n = 0.f;
  if (!USE_IG) {
    bi_r = bias[col];
    bi_z = bias[NH + col];
    bi_n = bias[2 * NH + col];
  }
  const float bnv = bn[col];

  float hreg[4] = {0.f, 0.f, 0.f, 0.f};

  unsigned* const hb0 = hbuf;
  unsigned* const hb1 = hbuf + NB * NH;

  for (int t = 0; t < NT; ++t) {
    const unsigned* hcur = (t & 1) ? hb1 : hb0;
    unsigned* hnxt = (t & 1) ? hb0 : hb1;

    int4v a[32];
    if (t > 0) {
      // combined poll+data attempts: each is ONE asm batch + one vmcnt(0).
      // The attempt that observes the flag already carries the data.
      const unsigned* hp = hcur + (size_t)mrow * NH + q * 8;
      const unsigned* fp = pollbase + (lane & 31);
      const unsigned tt = (unsigned)t;
      for (;;) {
        unsigned fv;
        load_batch(hp, fp, a, &fv);
        unsigned bad = ((int)fv < t) ? 1u : 0u;
#pragma unroll
        for (int i = 0; i < 32; ++i) {
#pragma unroll
          for (int j = 0; j < 4; ++j)
            bad |= ((unsigned)a[i][j] ^ tt) & 0xffffu;
        }
        if (__all((int)(bad == 0u))) break;
      }
    } else {
#pragma unroll
      for (int i = 0; i < 32; ++i) a[i] = (int4v){0, 0, 0, 0};
    }

    // IG loads (plain cached), after verify; hide under repack+MFMA.
    float igr[4], igz[4], ign[4];
    if (USE_IG) {
#pragma unroll
      for (int i = 0; i < 4; ++i) {
        const size_t base = ((size_t)(erow + i) * NT + t) * NG + col;
        igr[i] = bf2f(IG[base]);
        igz[i] = bf2f(IG[base + NH]);
        ign[i] = bf2f(IG[base + 2 * NH]);
      }
    }

    f32x4 ar = {0.f, 0.f, 0.f, 0.f};
    f32x4 az = {0.f, 0.f, 0.f, 0.f};
    f32x4 an = {0.f, 0.f, 0.f, 0.f};
    f32x4 ai = {0.f, 0.f, 0.f, 0.f};
#pragma unroll
    for (int kk = 0; kk < 16; ++kk) {
      // repack tagged dwords (value in hi16) -> bf16 short8 fragment
      const int4v dlo = a[2 * kk];
      const int4v dhi = a[2 * kk + 1];
      unsigned w0 = __builtin_amdgcn_perm((unsigned)dlo[1], (unsigned)dlo[0], 0x07060302u);
      unsigned w1 = __builtin_amdgcn_perm((unsigned)dlo[3], (unsigned)dlo[2], 0x07060302u);
      unsigned w2 = __builtin_amdgcn_perm((unsigned)dhi[1], (unsigned)dhi[0], 0x07060302u);
      unsigned w3 = __builtin_amdgcn_perm((unsigned)dhi[3], (unsigned)dhi[2], 0x07060302u);
      int4v wv = {(int)w0, (int)w1, (int)w2, (int)w3};
      short8 afk = __builtin_bit_cast(short8, wv);

      const short8 br  = Blds[((0 * 16 + kk) * 4 + q) * 32 + ci];
      const short8 bz  = Blds[((1 * 16 + kk) * 4 + q) * 32 + ci];
      const short8 bnn = Blds[((2 * 16 + kk) * 4 + q) * 32 + ci];
      ar = __builtin_amdgcn_mfma_f32_16x16x32_bf16(afk, br, ar, 0, 0, 0);
      az = __builtin_amdgcn_mfma_f32_16x16x32_bf16(afk, bz, az, 0, 0, 0);
      an = __builtin_amdgcn_mfma_f32_16x16x32_bf16(afk, bnn, an, 0, 0, 0);
      if (!USE_IG) {
        const float* xp = x + ((size_t)mrow * NT + t) * ND + kk * 32 + q * 8;
        short8 xa = pack8(*(const float4*)xp, *(const float4*)(xp + 4));
#pragma unroll
        for (int gt = 0; gt < 3; ++gt) {
          const float* wp = Wih + (size_t)(gt * NH + col) * ND + kk * 32 + q * 8;
          short8 wf = pack8(*(const float4*)wp, *(const float4*)(wp + 4));
          if (gt == 0) ar = __builtin_amdgcn_mfma_f32_16x16x32_bf16(xa, wf, ar, 0, 0, 0);
          if (gt == 1) az = __builtin_amdgcn_mfma_f32_16x16x32_bf16(xa, wf, az, 0, 0, 0);
          if (gt == 2) ai = __builtin_amdgcn_mfma_f32_16x16x32_bf16(xa, wf, ai, 0, 0, 0);
        }
      }
    }

    // gates + h update; tagged stores -> drain -> flag (R4 protocol)
    unsigned sv[4];
#pragma unroll
    for (int i = 0; i < 4; ++i) {
      float xr = USE_IG ? (ar[i] + igr[i]) : (ar[i] + bi_r);
      float xz = USE_IG ? (az[i] + igz[i]) : (az[i] + bi_z);
      float xin = USE_IG ? ign[i] : (ai[i] + bi_n);
      float r = sigmoid_f(xr);
      float z = sigmoid_f(xz);
      float n = tanh_f(xin + r * (an[i] + bnv));
      float hn2 = (1.f - z) * n + z * hreg[i];
      hreg[i] = hn2;
      sv[i] = ((unsigned)f2bf(hn2) << 16) | (unsigned)(t + 1);
      if (t == NT - 1) hfin[(size_t)(erow + i) * NH + col] = hn2;
    }
    if (t != NT - 1) {
      unsigned* sp2 = hnxt + (size_t)(erow + 2) * NH + col;  // +2-row base
      store_t4(sp2, sv[0], sv[1], sv[2], sv[3]);
      asm volatile("s_waitcnt vmcnt(0)" ::: "memory");  // drain before flag
      if (lane == 0) flag_store(myflag, (unsigned)(t + 1));
    }
  }
}

// ---------------------------------------------------------------------------
// out = h_T @ Wlin^T + blin; mu = cols [0,256), logvar = cols [256,512).
// ---------------------------------------------------------------------------
__global__ __launch_bounds__(256) void final_linear(
    const float* __restrict__ hfin, const float* __restrict__ Wlin,
    const float* __restrict__ blin, float* __restrict__ out) {
  __shared__ float sh[16 * 516];
  const int tid = threadIdx.x;
  const int b0 = blockIdx.y * 16, o0 = blockIdx.x * 16;

  for (int j = tid; j < 16 * 128; j += 256) {
    int row = j >> 7, kq = j & 127;
    *(float4*)&sh[row * 516 + kq * 4] =
        *(const float4*)(hfin + (size_t)(b0 + row) * NH + kq * 4);
  }
  __syncthreads();

  const int bi = tid & 15, oi = tid >> 4;
  const int o = o0 + oi;
  const float4* wp = (const float4*)(Wlin + (size_t)o * NH);
  float4 a4 = {0.f, 0.f, 0.f, 0.f};
  for (int k4 = 0; k4 < 128; ++k4) {
    float4 wv = wp[k4];
    float4 hv = *(const float4*)&sh[bi * 516 + k4 * 4];
    a4.x += wv.x * hv.x; a4.y += wv.y * hv.y;
    a4.z += wv.z * hv.z; a4.w += wv.w * hv.w;
  }
  float v = a4.x + a4.y + a4.z + a4.w + blin[o];
  int b = b0 + bi;
  if (o < 256) out[b * 256 + o] = v;
  else out[32768 + b * 256 + (o - 256)] = v;
}

// ---------------------------------------------------------------------------
extern "C" void kernel_launch(void* const* d_in, const int* in_sizes, int n_in,
                              void* d_out, int out_size, void* d_ws, size_t ws_size,
                              hipStream_t stream) {
  const float* x    = (const float*)d_in[0];
  const float* Wih  = (const float*)d_in[1];
  const float* Whh  = (const float*)d_in[2];
  const float* bias = (const float*)d_in[3];
  const float* bn   = (const float*)d_in[4];
  const float* Wlin = (const float*)d_in[5];
  const float* blin = (const float*)d_in[6];
  float* out = (float*)d_out;

  char* ws = (char*)d_ws;
  // layout: [hbuf u32 x2 524288][flags 1024][hfin 262144][IG 201326592]
  unsigned* hbuf     = (unsigned*)ws;
  unsigned* flags    = (unsigned*)(ws + 524288);
  float* hfin        = (float*)(ws + 525312);
  unsigned short* IG = (unsigned short*)(ws + 787456);
  const size_t need_min = 787456;
  const size_t need_ig  = 787456 + (size_t)NB * NT * NG * 2;  // ~203 MB
  if (ws_size < need_min) return;

  // zero tagged h buffers + flags (tag/flag 0 < any live value)
  hipMemsetAsync(ws, 0, 525312, stream);

  const bool useIG = (ws_size >= need_ig);
  if (useIG) {
    ig_gemm<<<dim3(512, 12), 256, 0, stream>>>(x, Wih, bias, IG);
    gru_rec<true><<<64, 256, 0, stream>>>(x, Wih, Whh, bias, bn, IG, hbuf, flags, hfin);
  } else {
    gru_rec<false><<<64, 256, 0, stream>>>(x, Wih, Whh, bias, bn, nullptr, hbuf, flags, hfin);
  }
  final_linear<<<dim3(32, 8), 256, 0, stream>>>(hfin, Wlin, blin, out);
}

// Round 16
// 4085.747 us; speedup vs baseline: 1.2453x; 1.2453x over previous
//
#include <hip/hip_runtime.h>
#include <stdint.h>

// ---------------------------------------------------------------------------
// GRU encoder (B=128,T=512,D=512,H=512,L=256), MI355X gfx950.
//
// R20: R14-EXACT ring (proven: gru_rec 1998us, sc1 device scope, drain-then-
// flag producer) with ONE change: the consumer's serial {poll -> load_h16}
// is replaced by a SINGLE-ASM pipelined poll+load:
//   - 4 flag polls kept in flight; loop { s_waitcnt vmcnt(3) -> check oldest
//     (v_cmp_ge + s_cmp_eq_u64 vcc,exec -> uniform branch) -> reissue }.
//     Sampling period ~RT/4 instead of RT (serial poll) -> cuts the
//     observation-jitter term (~0.4RT ~ 800cy/step).
//   - On success: issue the 16 h dwordx4 loads IMMEDIATELY (same asm), then
//     one s_waitcnt vmcnt(0) drains data + residual polls together (residual
//     polls are older -> free under the data RT).
// R18's silent corruption came from splitting issue/wait across asm blocks
// (in-flight loads target physical regs the compiler may remap). Here the
// whole sequence lives in ONE asm body; labels use %= for uniqueness.
// All 64 lanes poll flag[lane&31] (no divergence; duplicate polls harmless,
// flags are monotone). Exit condition vcc==exec = all active lanes see
// flag>=t. Producer/protocol/topology byte-identical to R14.
// R19 post-mortem: combined poll+data = ~2 full 512B attempts/step (FETCH
// 935MB) — tagged-u32 protocols 0-for-5, closed. This keeps R4/R14's
// drain->flag->cheap-poll structure and only shrinks the sampling latency.
// ---------------------------------------------------------------------------

typedef short short8 __attribute__((ext_vector_type(8)));
typedef float f32x4 __attribute__((ext_vector_type(4)));
typedef int int4v __attribute__((ext_vector_type(4)));

#define NB 128
#define NT 512
#define ND 512
#define NH 512
#define NG 1536  // 3H

__device__ __forceinline__ unsigned short f2bf(float f) {
  union { float f; unsigned u; } v; v.f = f;
  unsigned r = v.u + 0x7fffu + ((v.u >> 16) & 1u);  // RNE
  return (unsigned short)(r >> 16);
}
__device__ __forceinline__ float bf2f(unsigned short u) {
  union { unsigned u; float f; } v; v.u = ((unsigned)u) << 16; return v.f;
}
__device__ __forceinline__ float sigmoid_f(float x) {
  float e = __builtin_amdgcn_exp2f(-1.4426950408889634f * x);
  return __builtin_amdgcn_rcpf(1.0f + e);
}
__device__ __forceinline__ float tanh_f(float x) {
  float e = __builtin_amdgcn_exp2f(2.8853900817779268f * x);
  return 1.0f - 2.0f * __builtin_amdgcn_rcpf(1.0f + e);
}
__device__ __forceinline__ short8 pack8(float4 a, float4 b) {
  short8 s;
  s[0] = (short)f2bf(a.x); s[1] = (short)f2bf(a.y);
  s[2] = (short)f2bf(a.z); s[3] = (short)f2bf(a.w);
  s[4] = (short)f2bf(b.x); s[5] = (short)f2bf(b.y);
  s[6] = (short)f2bf(b.z); s[7] = (short)f2bf(b.w);
  return s;
}

// ---- fused pipelined poll + h load, ONE asm body (R18 lesson) -------------
// fp = this lane's flag pointer (flag[lane&31] of the row-half);
// tt = step t (VGPR); p = lane's h pointer (incl. +q*8 element offset).
// Loop: 4 polls in flight, wait vmcnt(3), check oldest, uniform-exit when
// ALL lanes see flag >= t, else reissue and rotate. On exit: issue 16
// dwordx4 h loads, then vmcnt(0) (drains data + residual polls).
__device__ __forceinline__ void poll_and_load(const unsigned* fp, unsigned tt,
                                              const unsigned short* p,
                                              int4v a[16]) {
  unsigned f0, f1, f2, f3;
  asm volatile(
      "global_load_dword %16, %21, off sc1\n\t"
      "global_load_dword %17, %21, off sc1\n\t"
      "global_load_dword %18, %21, off sc1\n\t"
      "global_load_dword %19, %21, off sc1\n\t"
      "Lp%=:\n\t"
      "s_waitcnt vmcnt(3)\n\t"
      "v_cmp_ge_u32 vcc, %16, %22\n\t"
      "s_cmp_eq_u64 vcc, exec\n\t"
      "s_cbranch_scc1 Ld%=\n\t"
      "global_load_dword %16, %21, off sc1\n\t"
      "s_waitcnt vmcnt(3)\n\t"
      "v_cmp_ge_u32 vcc, %17, %22\n\t"
      "s_cmp_eq_u64 vcc, exec\n\t"
      "s_cbranch_scc1 Ld%=\n\t"
      "global_load_dword %17, %21, off sc1\n\t"
      "s_waitcnt vmcnt(3)\n\t"
      "v_cmp_ge_u32 vcc, %18, %22\n\t"
      "s_cmp_eq_u64 vcc, exec\n\t"
      "s_cbranch_scc1 Ld%=\n\t"
      "global_load_dword %18, %21, off sc1\n\t"
      "s_waitcnt vmcnt(3)\n\t"
      "v_cmp_ge_u32 vcc, %19, %22\n\t"
      "s_cmp_eq_u64 vcc, exec\n\t"
      "s_cbranch_scc1 Ld%=\n\t"
      "global_load_dword %19, %21, off sc1\n\t"
      "s_branch Lp%=\n\t"
      "Ld%=:\n\t"
      "global_load_dwordx4 %0,  %20, off sc1\n\t"
      "global_load_dwordx4 %1,  %20, off offset:64 sc1\n\t"
      "global_load_dwordx4 %2,  %20, off offset:128 sc1\n\t"
      "global_load_dwordx4 %3,  %20, off offset:192 sc1\n\t"
      "global_load_dwordx4 %4,  %20, off offset:256 sc1\n\t"
      "global_load_dwordx4 %5,  %20, off offset:320 sc1\n\t"
      "global_load_dwordx4 %6,  %20, off offset:384 sc1\n\t"
      "global_load_dwordx4 %7,  %20, off offset:448 sc1\n\t"
      "global_load_dwordx4 %8,  %20, off offset:512 sc1\n\t"
      "global_load_dwordx4 %9,  %20, off offset:576 sc1\n\t"
      "global_load_dwordx4 %10, %20, off offset:640 sc1\n\t"
      "global_load_dwordx4 %11, %20, off offset:704 sc1\n\t"
      "global_load_dwordx4 %12, %20, off offset:768 sc1\n\t"
      "global_load_dwordx4 %13, %20, off offset:832 sc1\n\t"
      "global_load_dwordx4 %14, %20, off offset:896 sc1\n\t"
      "global_load_dwordx4 %15, %20, off offset:960 sc1\n\t"
      "s_waitcnt vmcnt(0)"
      : "=&v"(a[0]), "=&v"(a[1]), "=&v"(a[2]), "=&v"(a[3]),
        "=&v"(a[4]), "=&v"(a[5]), "=&v"(a[6]), "=&v"(a[7]),
        "=&v"(a[8]), "=&v"(a[9]), "=&v"(a[10]), "=&v"(a[11]),
        "=&v"(a[12]), "=&v"(a[13]), "=&v"(a[14]), "=&v"(a[15]),
        "=&v"(f0), "=&v"(f1), "=&v"(f2), "=&v"(f3)
      : "v"(p), "v"(fp), "v"(tt)
      : "memory", "vcc");
}

// 4 device-scope short stores (rows erow..erow+3, stride NH*2=1024B) + drain
// so the subsequent flag store implies device-wide visibility of this slice.
__device__ __forceinline__ void store_h4(unsigned short* p, unsigned v0,
                                         unsigned v1, unsigned v2, unsigned v3) {
  asm volatile(
      "global_store_short %0, %1, off sc1\n\t"
      "global_store_short %0, %2, off offset:1024 sc1\n\t"
      "global_store_short %0, %3, off offset:2048 sc1\n\t"
      "global_store_short %0, %4, off offset:3072 sc1\n\t"
      "s_waitcnt vmcnt(0)"
      :
      : "v"(p), "v"(v0), "v"(v1), "v"(v2), "v"(v3)
      : "memory");
}

__device__ __forceinline__ void flag_store(unsigned* p, unsigned v) {
  asm volatile("global_store_dword %0, %1, off sc1"
               :: "v"(p), "v"(v) : "memory");
}

// ---------------------------------------------------------------------------
// IG = x @ Wih^T + bias, bf16 out. M=65536, N=1536, K=512. (unchanged)
// ---------------------------------------------------------------------------
__global__ __launch_bounds__(256) void ig_gemm(
    const float* __restrict__ x, const float* __restrict__ Wih,
    const float* __restrict__ bias, unsigned short* __restrict__ IG) {
  __shared__ unsigned short As[128 * 40];
  __shared__ unsigned short Bs[128 * 40];
  const int tid = threadIdx.x;
  const int bm = blockIdx.x, bn = blockIdx.y;
  const int lane = tid & 63, w = tid >> 6;
  const int wm = w >> 1, wn = w & 1;
  const int l15 = lane & 15, q = lane >> 4;

  f32x4 acc[4][4] = {};

  for (int kt = 0; kt < 16; ++kt) {
    __syncthreads();
#pragma unroll
    for (int j = 0; j < 4; ++j) {
      int fi = tid + 256 * j;
      int row = fi >> 3, kq = fi & 7;
      float4 v = *(const float4*)(x + (size_t)(bm * 128 + row) * ND + kt * 32 + kq * 4);
      ushort4 s = {f2bf(v.x), f2bf(v.y), f2bf(v.z), f2bf(v.w)};
      *(ushort4*)&As[row * 40 + kq * 4] = s;
    }
#pragma unroll
    for (int j = 0; j < 4; ++j) {
      int fi = tid + 256 * j;
      int row = fi >> 3, kq = fi & 7;
      float4 v = *(const float4*)(Wih + (size_t)(bn * 128 + row) * ND + kt * 32 + kq * 4);
      ushort4 s = {f2bf(v.x), f2bf(v.y), f2bf(v.z), f2bf(v.w)};
      *(ushort4*)&Bs[row * 40 + kq * 4] = s;
    }
    __syncthreads();

    short8 af[4], bfv[4];
#pragma unroll
    for (int tm = 0; tm < 4; ++tm)
      af[tm] = *(const short8*)&As[(wm * 64 + tm * 16 + l15) * 40 + q * 8];
#pragma unroll
    for (int tn = 0; tn < 4; ++tn)
      bfv[tn] = *(const short8*)&Bs[(wn * 64 + tn * 16 + l15) * 40 + q * 8];
#pragma unroll
    for (int tm = 0; tm < 4; ++tm)
#pragma unroll
      for (int tn = 0; tn < 4; ++tn)
        acc[tm][tn] = __builtin_amdgcn_mfma_f32_16x16x32_bf16(af[tm], bfv[tn], acc[tm][tn], 0, 0, 0);
  }

#pragma unroll
  for (int tm = 0; tm < 4; ++tm) {
#pragma unroll
    for (int tn = 0; tn < 4; ++tn) {
      int col = bn * 128 + wn * 64 + tn * 16 + l15;
      float bb = bias[col];
#pragma unroll
      for (int i = 0; i < 4; ++i) {
        int row = bm * 128 + wm * 64 + tm * 16 + q * 4 + i;
        IG[(size_t)row * NG + col] = f2bf(acc[tm][tn][i] + bb);
      }
    }
  }
}

// ---------------------------------------------------------------------------
// Persistent GRU recurrence. 64 blocks x 256 threads. (R14 topology/protocol)
// block = (group g of 32 batch rows, chunk c of 32 h-cols).
// wave (wm,wn): rows [b0+wm*16, +16), cols [c*32+wn*16, +16).
// flags[((g*2+wm)*16+c)*2+wn] = step count written by that producer wave
// (h stores drained at device scope before the flag store).
// ---------------------------------------------------------------------------
template <bool USE_IG>
__global__ __launch_bounds__(256, 1) void gru_rec(
    const float* __restrict__ x, const float* __restrict__ Wih,
    const float* __restrict__ Whh, const float* __restrict__ bias,
    const float* __restrict__ bn, const unsigned short* __restrict__ IG,
    unsigned short* __restrict__ hbuf, unsigned* __restrict__ flags,
    float* __restrict__ hfin) {
  const int tid = threadIdx.x;
  const int lane = tid & 63;
  const int w = tid >> 6;
  const int wm = w >> 1, wn = w & 1;
  const int l15 = lane & 15, q = lane >> 4;
  const int g = blockIdx.x >> 4;   // 4 groups
  const int c = blockIdx.x & 15;   // 16 col-chunks of 32
  const int b0 = g * 32;
  const int col = c * 32 + wn * 16 + l15;  // this lane's h column
  const int mrow = b0 + wm * 16 + l15;     // A-fragment batch row
  const int erow = b0 + wm * 16 + q * 4;   // C-layout batch row base

  unsigned* const myflag = flags + ((g * 2 + wm) * 16 + c) * 2 + wn;
  const unsigned* const pollbase = flags + (g * 2 + wm) * 32;  // 32 flags
  const unsigned* const myfp = pollbase + (lane & 31);         // all 64 lanes

  // Whh B-fragments -> registers: 3 gates x 16 k-chunks (192 VGPRs)
  short8 bfr[3][16];
#pragma unroll
  for (int gt = 0; gt < 3; ++gt) {
    const float* src = Whh + (size_t)(gt * NH + col) * NH + q * 8;
#pragma unroll
    for (int kk = 0; kk < 16; ++kk) {
      float4 v0 = *(const float4*)(src + kk * 32);
      float4 v1 = *(const float4*)(src + kk * 32 + 4);
      bfr[gt][kk] = pack8(v0, v1);
    }
  }

  float bi_r = 0.f, bi_z = 0.f, bi_n = 0.f;
  if (!USE_IG) {
    bi_r = bias[col];
    bi_z = bias[NH + col];
    bi_n = bias[2 * NH + col];
  }
  const float bnv = bn[col];

  float hreg[4] = {0.f, 0.f, 0.f, 0.f};

  unsigned short* const hb0 = hbuf;
  unsigned short* const hb1 = hbuf + NB * NH;

  for (int t = 0; t < NT; ++t) {
    const unsigned short* hcur = (t & 1) ? hb1 : hb0;
    unsigned short* hnxt = (t & 1) ? hb0 : hb1;

    // IG loads first (plain cached loads; drained by the fused asm's final
    // vmcnt(0) — same behavior as R14, off the flag-wait critical path).
    float igr[4], igz[4], ign[4];
    if (USE_IG) {
#pragma unroll
      for (int i = 0; i < 4; ++i) {
        const size_t base = ((size_t)(erow + i) * NT + t) * NG + col;
        igr[i] = bf2f(IG[base]);
        igz[i] = bf2f(IG[base + NH]);
        ign[i] = bf2f(IG[base + 2 * NH]);
      }
    }

    int4v araw[16];
    if (t > 0) {
      // fused pipelined poll (period ~RT/4) + h data load, one asm body.
      poll_and_load(myfp, (unsigned)t, hcur + (size_t)mrow * NH + q * 8, araw);
    } else {
      // h_0 = 0: no poll, no load
#pragma unroll
      for (int kk = 0; kk < 16; ++kk) araw[kk] = (int4v){0, 0, 0, 0};
    }

    f32x4 ar = {0.f, 0.f, 0.f, 0.f};
    f32x4 az = {0.f, 0.f, 0.f, 0.f};
    f32x4 an = {0.f, 0.f, 0.f, 0.f};
    f32x4 ai = {0.f, 0.f, 0.f, 0.f};
#pragma unroll
    for (int kk = 0; kk < 16; ++kk) {
      short8 afk = __builtin_bit_cast(short8, araw[kk]);
      ar = __builtin_amdgcn_mfma_f32_16x16x32_bf16(afk, bfr[0][kk], ar, 0, 0, 0);
      az = __builtin_amdgcn_mfma_f32_16x16x32_bf16(afk, bfr[1][kk], az, 0, 0, 0);
      an = __builtin_amdgcn_mfma_f32_16x16x32_bf16(afk, bfr[2][kk], an, 0, 0, 0);
      if (!USE_IG) {
        const float* xp = x + ((size_t)mrow * NT + t) * ND + kk * 32 + q * 8;
        short8 xa = pack8(*(const float4*)xp, *(const float4*)(xp + 4));
#pragma unroll
        for (int gt = 0; gt < 3; ++gt) {
          const float* wp = Wih + (size_t)(gt * NH + col) * ND + kk * 32 + q * 8;
          short8 wf = pack8(*(const float4*)wp, *(const float4*)(wp + 4));
          if (gt == 0) ar = __builtin_amdgcn_mfma_f32_16x16x32_bf16(xa, wf, ar, 0, 0, 0);
          if (gt == 1) az = __builtin_amdgcn_mfma_f32_16x16x32_bf16(xa, wf, az, 0, 0, 0);
          if (gt == 2) ai = __builtin_amdgcn_mfma_f32_16x16x32_bf16(xa, wf, ai, 0, 0, 0);
        }
      }
    }

    // gates + h update; store via device-scope short stores, drain, flag
    unsigned sv[4];
#pragma unroll
    for (int i = 0; i < 4; ++i) {
      float xr = USE_IG ? (ar[i] + igr[i]) : (ar[i] + bi_r);
      float xz = USE_IG ? (az[i] + igz[i]) : (az[i] + bi_z);
      float xin = USE_IG ? ign[i] : (ai[i] + bi_n);
      float r = sigmoid_f(xr);
      float z = sigmoid_f(xz);
      float n = tanh_f(xin + r * (an[i] + bnv));
      float hn2 = (1.f - z) * n + z * hreg[i];
      hreg[i] = hn2;
      sv[i] = (unsigned)f2bf(hn2);
      if (t == NT - 1) hfin[(size_t)(erow + i) * NH + col] = hn2;
    }
    if (t != NT - 1) {
      store_h4(hnxt + (size_t)erow * NH + col, sv[0], sv[1], sv[2], sv[3]);
      if (lane == 0) flag_store(myflag, (unsigned)(t + 1));
    }
  }
}

// ---------------------------------------------------------------------------
// out = h_T @ Wlin^T + blin; mu = cols [0,256), logvar = cols [256,512).
// ---------------------------------------------------------------------------
__global__ __launch_bounds__(256) void final_linear(
    const float* __restrict__ hfin, const float* __restrict__ Wlin,
    const float* __restrict__ blin, float* __restrict__ out) {
  __shared__ float sh[16 * 516];
  const int tid = threadIdx.x;
  const int b0 = blockIdx.y * 16, o0 = blockIdx.x * 16;

  for (int j = tid; j < 16 * 128; j += 256) {
    int row = j >> 7, kq = j & 127;
    *(float4*)&sh[row * 516 + kq * 4] =
        *(const float4*)(hfin + (size_t)(b0 + row) * NH + kq * 4);
  }
  __syncthreads();

  const int bi = tid & 15, oi = tid >> 4;
  const int o = o0 + oi;
  const float4* wp = (const float4*)(Wlin + (size_t)o * NH);
  float4 a4 = {0.f, 0.f, 0.f, 0.f};
  for (int k4 = 0; k4 < 128; ++k4) {
    float4 wv = wp[k4];
    float4 hv = *(const float4*)&sh[bi * 516 + k4 * 4];
    a4.x += wv.x * hv.x; a4.y += wv.y * hv.y;
    a4.z += wv.z * hv.z; a4.w += wv.w * hv.w;
  }
  float v = a4.x + a4.y + a4.z + a4.w + blin[o];
  int b = b0 + bi;
  if (o < 256) out[b * 256 + o] = v;
  else out[32768 + b * 256 + (o - 256)] = v;
}

// ---------------------------------------------------------------------------
extern "C" void kernel_launch(void* const* d_in, const int* in_sizes, int n_in,
                              void* d_out, int out_size, void* d_ws, size_t ws_size,
                              hipStream_t stream) {
  const float* x    = (const float*)d_in[0];
  const float* Wih  = (const float*)d_in[1];
  const float* Whh  = (const float*)d_in[2];
  const float* bias = (const float*)d_in[3];
  const float* bn   = (const float*)d_in[4];
  const float* Wlin = (const float*)d_in[5];
  const float* blin = (const float*)d_in[6];
  float* out = (float*)d_out;

  char* ws = (char*)d_ws;
  // layout: [hbuf 262144][flags 1024][hfin 262144][IG 201326592]
  unsigned short* hbuf = (unsigned short*)ws;
  unsigned* flags      = (unsigned*)(ws + 262144);
  float* hfin          = (float*)(ws + 263168);
  unsigned short* IG   = (unsigned short*)(ws + 525312);
  const size_t need_min = 525312;
  const size_t need_ig  = 525312 + (size_t)NB * NT * NG * 2;  // ~203 MB
  if (ws_size < need_min) return;

  // zero flags only (h_0 is synthesized in registers; hbuf needs no init)
  hipMemsetAsync(ws + 262144, 0, 1024, stream);

  const bool useIG = (ws_size >= need_ig);
  if (useIG) {
    ig_gemm<<<dim3(512, 12), 256, 0, stream>>>(x, Wih, bias, IG);
    gru_rec<true><<<64, 256, 0, stream>>>(x, Wih, Whh, bias, bn, IG, hbuf, flags, hfin);
  } else {
    gru_rec<false><<<64, 256, 0, stream>>>(x, Wih, Whh, bias, bn, nullptr, hbuf, flags, hfin);
  }
  final_linear<<<dim3(32, 8), 256, 0, stream>>>(hfin, Wlin, blin, out);
}